// Round 16
// baseline (63.105 us; speedup 1.0000x reference)
//
#include <hip/hip_runtime.h>
#include <stdint.h>

// Two-kernel 3x3 neighborhood-attention.
//  K1 coef6_kernel: apply-shaped loads + register accumulation + BIG GRID.
//    Block = 64-px segment of a row (2048 blocks -> real TLP; R14's coef5 had
//    the right load shape but only 2 blocks/CU). 256 threads = 16 quads x
//    16 ch-groups (4ch each): 16 float4 loads/thread + masked edge scalars.
//    Margins via __shfl within wave; segment edges via masked global scalars
//    (reflect at image edges falls out exactly). Reduce: shfl_xor(16,32) over
//    ch-groups, then [19][4][64] LDS over waves, softmax, coalesced stores.
//  K2 apply_kernel: float4 streaming out = exp(-(nbr-ref)^2)*sum_k coef_k*nbr_k.
// Shapes: [b=2, c=64, h=256, w=256] fp32.

constexpr int C = 64, H = 256, W = 256, HW = H * W;
constexpr int B = 2, PIX = B * HW;
constexpr int SEG = 64;             // pixels per block

// ---------------- K1: coefficient kernel (big-grid, apply-shaped) ----------------
__global__ __launch_bounds__(256) void coef6_kernel(const float* __restrict__ nbr,
                                                    const float* __restrict__ ref,
                                                    float* __restrict__ coef) {
  __shared__ float part[19][4][SEG];   // 19,456 B

  const int tid  = threadIdx.x;
  const int lane = tid & 63;
  const int wv   = tid >> 6;          // channel quarter 0..3
  const int q    = lane & 15;         // quad within segment (x0 = seg*64 + 4q)
  const int g    = lane >> 4;         // 4-channel subgroup 0..3

  // XCD band swizzle, bijective on [0,2048)
  const int bid = ((blockIdx.x & 7) << 8) | (blockIdx.x >> 3);
  const int by  = bid >> 2;           // b*256 + y
  const int seg = bid & 3;            // x segment 0..3
  const int b   = by >> 8;
  const int y   = by & 255;
  const int ym  = (y == 0)     ? 1     : y - 1;   // jnp reflect
  const int yp  = (y == H - 1) ? H - 2 : y + 1;
  const int x0  = seg * SEG + q * 4;

  const float* nbase = nbr + (size_t)b * C * HW;
  const float* rrow  = ref + (size_t)b * C * HW + y * W;
  const int off3[3] = {ym * W, y * W, yp * W};
  const int ch0 = wv * 16 + g * 4;    // this thread's first channel

  float dt[4][9], sq[4][9], sr[4];
#pragma unroll
  for (int e = 0; e < 4; ++e) {
    sr[e] = 0.f;
#pragma unroll
    for (int k = 0; k < 9; ++k) { dt[e][k] = 0.f; sq[e][k] = 0.f; }
  }

#pragma unroll 2
  for (int cc = 0; cc < 4; ++cc) {
    const float* cb = nbase + (size_t)(ch0 + cc) * HW;
    const float4 am = *(const float4*)(cb + off3[0] + x0);
    const float4 ac = *(const float4*)(cb + off3[1] + x0);
    const float4 ap = *(const float4*)(cb + off3[2] + x0);
    const float4 rf = *(const float4*)(rrow + (size_t)(ch0 + cc) * HW + x0);
    const float rfe[4] = {rf.x, rf.y, rf.z, rf.w};
    sr[0] = fmaf(rfe[0], rfe[0], sr[0]);
    sr[1] = fmaf(rfe[1], rfe[1], sr[1]);
    sr[2] = fmaf(rfe[2], rfe[2], sr[2]);
    sr[3] = fmaf(rfe[3], rfe[3], sr[3]);

    const float4 rows[3] = {am, ac, ap};
#pragma unroll
    for (int r = 0; r < 3; ++r) {
      const float4 v = rows[r];
      float L = __shfl(v.w, lane - 1);     // same-g neighbor quad for q=1..15
      float R = __shfl(v.x, lane + 1);     // same-g neighbor quad for q=0..14
      if (q == 0)  L = (x0 == 0)       ? v.y : cb[off3[r] + x0 - 1];   // reflect / seg edge
      if (q == 15) R = (x0 == W - 4)   ? v.z : cb[off3[r] + x0 + 4];   // reflect / seg edge
      const float win[6] = {L, v.x, v.y, v.z, v.w, R};
      float w2[6];
#pragma unroll
      for (int i = 0; i < 6; ++i) w2[i] = win[i] * win[i];
      const int kb = r * 3;
#pragma unroll
      for (int e = 0; e < 4; ++e) {
#pragma unroll
        for (int cx = 0; cx < 3; ++cx) {
          dt[e][kb + cx] = fmaf(rfe[e], win[e + cx], dt[e][kb + cx]);
          sq[e][kb + cx] += w2[e + cx];
        }
      }
    }
  }

  // ---- intra-wave reduce over the 4 channel subgroups (xor 16, 32) ----
#pragma unroll
  for (int m = 16; m < 64; m <<= 1) {
#pragma unroll
    for (int e = 0; e < 4; ++e) {
      sr[e] += __shfl_xor(sr[e], m);
#pragma unroll
      for (int k = 0; k < 9; ++k) {
        dt[e][k] += __shfl_xor(dt[e][k], m);
        sq[e][k] += __shfl_xor(sq[e][k], m);
      }
    }
  }

  // ---- publish per-wave partials (lanes g==0 hold full 16-ch sums) ----
  if (g == 0) {
#pragma unroll
    for (int k = 0; k < 9; ++k) {
      *(float4*)&part[k][wv][q * 4]     = float4{dt[0][k], dt[1][k], dt[2][k], dt[3][k]};
      *(float4*)&part[9 + k][wv][q * 4] = float4{sq[0][k], sq[1][k], sq[2][k], sq[3][k]};
    }
    *(float4*)&part[18][wv][q * 4] = float4{sr[0], sr[1], sr[2], sr[3]};
  }
  __syncthreads();

  // ---- cross-wave combine + softmax (redundant in all waves; wv0 stores) ----
  const int px = lane;                 // pixel within segment
  float td[9], tq[9];
#pragma unroll
  for (int k = 0; k < 9; ++k) {
    td[k] = part[k][0][px] + part[k][1][px] + part[k][2][px] + part[k][3][px];
    tq[k] = part[9 + k][0][px] + part[9 + k][1][px] + part[9 + k][2][px] + part[9 + k][3][px];
  }
  const float tsr = part[18][0][px] + part[18][1][px] + part[18][2][px] + part[18][3][px];

  const float invr = __frsqrt_rn(fmaxf(tsr, 1e-24f));
  float d[9], invp[9];
  float mx = -INFINITY;
#pragma unroll
  for (int k = 0; k < 9; ++k) {
    invp[k] = __frsqrt_rn(fmaxf(tq[k], 1e-24f));
    d[k]    = td[k] * invr * invp[k];
    mx      = fmaxf(mx, d[k]);
  }
  float s = 0.f;
  float cf[9];
#pragma unroll
  for (int k = 0; k < 9; ++k) {
    cf[k] = __expf(d[k] - mx);
    s += cf[k];
  }
  const float sinv = 1.0f / s;

  if (wv == 0) {
    const int pix = by * W + seg * SEG + px;
#pragma unroll
    for (int k = 0; k < 9; ++k)
      coef[(size_t)k * PIX + pix] = cf[k] * sinv * invp[k];   // patch l2norm folded
  }
}

// ---------------- K2: apply kernel (proven; XCD swizzle, grid=4096) ----------------
__global__ __launch_bounds__(256) void apply_kernel(const float* __restrict__ nbr,
                                                    const float* __restrict__ ref,
                                                    const float* __restrict__ coef,
                                                    float* __restrict__ out) {
  const int blk  = ((blockIdx.x & 7) << 9) | (blockIdx.x >> 3);  // bijective on [0,4096)
  const int gid  = blk * 256 + threadIdx.x;
  const int lane = gid & 63;
  const int x0   = lane * 4;
  const int t    = gid >> 6;
  const int y    = t & 255;
  const int u    = t >> 8;
  const int b    = u >> 5;
  const int c0   = (u & 31) * 2;

  const int ym = (y == 0)     ? 1     : y - 1;
  const int yp = (y == H - 1) ? H - 2 : y + 1;

  const float* n0  = nbr + ((size_t)b * C + c0) * HW;
  const float* n1  = n0 + HW;
  const float* r0p = ref + ((size_t)b * C + c0) * HW;
  float*       o0  = out + ((size_t)b * C + c0) * HW;

  const float4 a0 = *(const float4*)(n0 + ym * W + x0);
  const float4 a1 = *(const float4*)(n0 + y  * W + x0);
  const float4 a2 = *(const float4*)(n0 + yp * W + x0);
  const float4 b0 = *(const float4*)(n1 + ym * W + x0);
  const float4 b1 = *(const float4*)(n1 + y  * W + x0);
  const float4 b2 = *(const float4*)(n1 + yp * W + x0);
  const float4 f0 = *(const float4*)(r0p + y * W + x0);
  const float4 f1 = *(const float4*)(r0p + HW + y * W + x0);

  float La0 = __shfl(a0.w, lane - 1), Ra0 = __shfl(a0.x, lane + 1);
  float La1 = __shfl(a1.w, lane - 1), Ra1 = __shfl(a1.x, lane + 1);
  float La2 = __shfl(a2.w, lane - 1), Ra2 = __shfl(a2.x, lane + 1);
  float Lb0 = __shfl(b0.w, lane - 1), Rb0 = __shfl(b0.x, lane + 1);
  float Lb1 = __shfl(b1.w, lane - 1), Rb1 = __shfl(b1.x, lane + 1);
  float Lb2 = __shfl(b2.w, lane - 1), Rb2 = __shfl(b2.x, lane + 1);
  if (lane == 0)  { La0 = a0.y; La1 = a1.y; La2 = a2.y; Lb0 = b0.y; Lb1 = b1.y; Lb2 = b2.y; }
  if (lane == 63) { Ra0 = a0.z; Ra1 = a1.z; Ra2 = a2.z; Rb0 = b0.z; Rb1 = b1.z; Rb2 = b2.z; }

  float va[3][6] = {{La0, a0.x, a0.y, a0.z, a0.w, Ra0},
                    {La1, a1.x, a1.y, a1.z, a1.w, Ra1},
                    {La2, a2.x, a2.y, a2.z, a2.w, Ra2}};
  float vb[3][6] = {{Lb0, b0.x, b0.y, b0.z, b0.w, Rb0},
                    {Lb1, b1.x, b1.y, b1.z, b1.w, Rb1},
                    {Lb2, b2.x, b2.y, b2.z, b2.w, Rb2}};

  const int cbase = b * HW + y * W + x0;
  float aga[4] = {0.f, 0.f, 0.f, 0.f};
  float agb[4] = {0.f, 0.f, 0.f, 0.f};
#pragma unroll
  for (int k = 0; k < 9; ++k) {
    const float4 cf = *(const float4*)(coef + (size_t)k * PIX + cbase);
    const int r  = k / 3;
    const int cx = k % 3;
    const float cfe[4] = {cf.x, cf.y, cf.z, cf.w};
#pragma unroll
    for (int e = 0; e < 4; ++e) {
      aga[e] = fmaf(cfe[e], va[r][e + cx], aga[e]);
      agb[e] = fmaf(cfe[e], vb[r][e + cx], agb[e]);
    }
  }

  const float ctra[4] = {a1.x, a1.y, a1.z, a1.w};
  const float ctrb[4] = {b1.x, b1.y, b1.z, b1.w};
  const float rfa[4]  = {f0.x, f0.y, f0.z, f0.w};
  const float rfb[4]  = {f1.x, f1.y, f1.z, f1.w};
  float oae[4], obe[4];
#pragma unroll
  for (int e = 0; e < 4; ++e) {
    const float da = ctra[e] - rfa[e];
    const float db = ctrb[e] - rfb[e];
    oae[e] = aga[e] * __expf(-(da * da));
    obe[e] = agb[e] * __expf(-(db * db));
  }
  float4 oa, ob4;
  oa.x = oae[0]; oa.y = oae[1]; oa.z = oae[2]; oa.w = oae[3];
  ob4.x = obe[0]; ob4.y = obe[1]; ob4.z = obe[2]; ob4.w = obe[3];

  *(float4*)(o0 + y * W + x0) = oa;
  *(float4*)(o0 + HW + y * W + x0) = ob4;
}

// ---------------- fallback: R4 fused kernel (if ws too small) ----------------
__global__ __launch_bounds__(256) void fused_nbr_attn(const float* __restrict__ nbr,
                                                      const float* __restrict__ ref,
                                                      float* __restrict__ out) {
  const int tid  = threadIdx.x;
  const int lane = tid & 63;
  const int wv   = tid >> 6;
  const int px   = lane & 7;
  const int cg   = lane >> 3;

  const int pix = blockIdx.x * 32 + wv * 8 + px;
  const int b   = pix >> 16;
  const int p   = pix & (HW - 1);
  const int y   = p >> 8;
  const int x   = p & (W - 1);

  const int ym = (y == 0)     ? 1     : y - 1;
  const int yp = (y == H - 1) ? H - 2 : y + 1;
  const int xm = (x == 0)     ? 1     : x - 1;
  const int xp = (x == W - 1) ? W - 2 : x + 1;

  int off[9];
  off[0] = ym * W + xm; off[1] = ym * W + x; off[2] = ym * W + xp;
  off[3] = y  * W + xm; off[4] = y  * W + x; off[5] = y  * W + xp;
  off[6] = yp * W + xm; off[7] = yp * W + x; off[8] = yp * W + xp;
  const int ctr = y * W + x;

  const float* nb = nbr + ((size_t)b * C + cg * 8) * HW;
  const float* rb = ref + ((size_t)b * C + cg * 8) * HW;
  float*       ob = out + ((size_t)b * C + cg * 8) * HW;

  float v[8][9], r[8];
#pragma unroll
  for (int j = 0; j < 8; ++j) {
    r[j] = rb[j * HW + ctr];
#pragma unroll
    for (int k = 0; k < 9; ++k) v[j][k] = nb[j * HW + off[k]];
  }
  float sr = 0.f;
  float dot[9], ss[9];
#pragma unroll
  for (int k = 0; k < 9; ++k) { dot[k] = 0.f; ss[k] = 0.f; }
#pragma unroll
  for (int j = 0; j < 8; ++j) {
    sr = fmaf(r[j], r[j], sr);
#pragma unroll
    for (int k = 0; k < 9; ++k) {
      dot[k] = fmaf(r[j], v[j][k], dot[k]);
      ss[k]  = fmaf(v[j][k], v[j][k], ss[k]);
    }
  }
#pragma unroll
  for (int m = 8; m < 64; m <<= 1) {
    sr += __shfl_xor(sr, m);
#pragma unroll
    for (int k = 0; k < 9; ++k) {
      dot[k] += __shfl_xor(dot[k], m);
      ss[k]  += __shfl_xor(ss[k], m);
    }
  }
  const float invr = __frsqrt_rn(fmaxf(sr, 1e-24f));
  float d[9], invp[9];
  float mx = -INFINITY;
#pragma unroll
  for (int k = 0; k < 9; ++k) {
    invp[k] = __frsqrt_rn(fmaxf(ss[k], 1e-24f));
    d[k]    = dot[k] * invr * invp[k];
    mx      = fmaxf(mx, d[k]);
  }
  float s = 0.f;
  float coef[9];
#pragma unroll
  for (int k = 0; k < 9; ++k) {
    const float e = __expf(d[k] - mx);
    coef[k] = e;
    s += e;
  }
  const float sinv = 1.0f / s;
#pragma unroll
  for (int k = 0; k < 9; ++k) coef[k] *= sinv * invp[k];
#pragma unroll
  for (int j = 0; j < 8; ++j) {
    float a = 0.f;
#pragma unroll
    for (int k = 0; k < 9; ++k) a = fmaf(coef[k], v[j][k], a);
    const float diff = v[j][4] - r[j];
    const float wd   = __expf(-(diff * diff));
    ob[j * HW + ctr] = a * wd;
  }
}

extern "C" void kernel_launch(void* const* d_in, const int* in_sizes, int n_in,
                              void* d_out, int out_size, void* d_ws, size_t ws_size,
                              hipStream_t stream) {
  const float* nbr = (const float*)d_in[0];
  const float* ref = (const float*)d_in[1];
  float*       out = (float*)d_out;
  const size_t coef_bytes = (size_t)9 * PIX * sizeof(float);

  if (ws_size >= coef_bytes) {
    float* coef = (float*)d_ws;
    coef6_kernel<<<dim3(PIX / SEG), dim3(256), 0, stream>>>(nbr, ref, coef);  // 2048 seg-blocks
    apply_kernel<<<dim3(PIX / 4 * (C / 2) / 256), dim3(256), 0, stream>>>(nbr, ref, coef, out);  // 4096
  } else {
    fused_nbr_attn<<<dim3(PIX / 32), dim3(256), 0, stream>>>(nbr, ref, out);
  }
}

// Round 17
// 42.152 us; speedup vs baseline: 1.4971x; 1.4971x over previous
//
#include <hip/hip_runtime.h>
#include <stdint.h>

// Two-kernel 3x3 neighborhood-attention.
//  K1 coef7_kernel: coef5's load shape (block=row, wave=16ch quarter, lane=quad,
//    fully-coalesced 1KB float4 instrs, shfl margins) + register-pressure fix:
//    (a) S-collapse: sq[4][9] -> s2[3][6] window sumsq (sq[e][k]=s2[r][e+k%3],
//        bit-identical), accumulators 76 -> 58;
//    (b) 16 float4 loads per 4-ch burst staged in NAMED registers before any
//        consume (R6's proven lever), unroll 1, __launch_bounds__(256,2)
//        -> load depth no longer starved by accumulators.
//  K2 apply_kernel: float4 streaming out = exp(-(nbr-ref)^2)*sum_k coef_k*nbr_k.
// Shapes: [b=2, c=64, h=256, w=256] fp32.

constexpr int C = 64, H = 256, W = 256, HW = H * W;
constexpr int B = 2, PIX = B * HW;

// ---------------- K1: coefficient kernel ----------------
__global__ __launch_bounds__(256, 2) void coef7_kernel(const float* __restrict__ nbr,
                                                       const float* __restrict__ ref,
                                                       float* __restrict__ coef) {
  __shared__ float part[19][4][W];    // 77,824 B

  const int tid  = threadIdx.x;
  const int lane = tid & 63;          // quad index; x0 = 4*lane
  const int wv   = tid >> 6;          // channel quarter 0..3
  const int x0   = lane * 4;

  // XCD band swizzle: 512 blocks, bijective
  const int by = ((blockIdx.x & 7) << 6) | (blockIdx.x >> 3);
  const int b  = by >> 8;
  const int y  = by & 255;
  const int ym = (y == 0)     ? 1     : y - 1;   // jnp reflect
  const int yp = (y == H - 1) ? H - 2 : y + 1;

  const float* nbase = nbr + (size_t)b * C * HW;
  const float* rrow  = ref + (size_t)b * C * HW + y * W;
  const int oM = ym * W, oC = y * W, oP = yp * W;
  const int c0 = wv * 16;

  float dt[4][9], s2[3][6], sr[4];
#pragma unroll
  for (int e = 0; e < 4; ++e) {
    sr[e] = 0.f;
#pragma unroll
    for (int k = 0; k < 9; ++k) dt[e][k] = 0.f;
  }
#pragma unroll
  for (int r = 0; r < 3; ++r)
#pragma unroll
    for (int i = 0; i < 6; ++i) s2[r][i] = 0.f;

  auto consume = [&](const float4 am, const float4 ac, const float4 ap, const float4 rf) {
    const float rfe[4] = {rf.x, rf.y, rf.z, rf.w};
    sr[0] = fmaf(rfe[0], rfe[0], sr[0]);
    sr[1] = fmaf(rfe[1], rfe[1], sr[1]);
    sr[2] = fmaf(rfe[2], rfe[2], sr[2]);
    sr[3] = fmaf(rfe[3], rfe[3], sr[3]);
    const float4 rows[3] = {am, ac, ap};
#pragma unroll
    for (int r = 0; r < 3; ++r) {
      const float4 v = rows[r];
      float L = __shfl(v.w, lane - 1);
      float R = __shfl(v.x, lane + 1);
      if (lane == 0)  L = v.y;        // reflect: x=-1 -> 1
      if (lane == 63) R = v.z;        // reflect: x=256 -> 254
      const float win[6] = {L, v.x, v.y, v.z, v.w, R};
#pragma unroll
      for (int i = 0; i < 6; ++i) s2[r][i] = fmaf(win[i], win[i], s2[r][i]);
      const int kb = r * 3;
#pragma unroll
      for (int e = 0; e < 4; ++e)
#pragma unroll
        for (int cx = 0; cx < 3; ++cx)
          dt[e][kb + cx] = fmaf(rfe[e], win[e + cx], dt[e][kb + cx]);
    }
  };

#pragma unroll 1
  for (int cc4 = 0; cc4 < 16; cc4 += 4) {
    const float* p0 = nbase + (size_t)(c0 + cc4 + 0) * HW;
    const float* p1 = nbase + (size_t)(c0 + cc4 + 1) * HW;
    const float* p2 = nbase + (size_t)(c0 + cc4 + 2) * HW;
    const float* p3 = nbase + (size_t)(c0 + cc4 + 3) * HW;
    // stage all 16 float4s in named registers before any consume
    const float4 a0m = *(const float4*)(p0 + oM + x0);
    const float4 a0c = *(const float4*)(p0 + oC + x0);
    const float4 a0p = *(const float4*)(p0 + oP + x0);
    const float4 f0  = *(const float4*)(rrow + (size_t)(c0 + cc4 + 0) * HW + x0);
    const float4 a1m = *(const float4*)(p1 + oM + x0);
    const float4 a1c = *(const float4*)(p1 + oC + x0);
    const float4 a1p = *(const float4*)(p1 + oP + x0);
    const float4 f1  = *(const float4*)(rrow + (size_t)(c0 + cc4 + 1) * HW + x0);
    const float4 a2m = *(const float4*)(p2 + oM + x0);
    const float4 a2c = *(const float4*)(p2 + oC + x0);
    const float4 a2p = *(const float4*)(p2 + oP + x0);
    const float4 f2  = *(const float4*)(rrow + (size_t)(c0 + cc4 + 2) * HW + x0);
    const float4 a3m = *(const float4*)(p3 + oM + x0);
    const float4 a3c = *(const float4*)(p3 + oC + x0);
    const float4 a3p = *(const float4*)(p3 + oP + x0);
    const float4 f3  = *(const float4*)(rrow + (size_t)(c0 + cc4 + 3) * HW + x0);

    consume(a0m, a0c, a0p, f0);
    consume(a1m, a1c, a1p, f1);
    consume(a2m, a2c, a2p, f2);
    consume(a3m, a3c, a3p, f3);
  }

  // ---- one-shot cross-wave reduce through LDS ----
#pragma unroll
  for (int k = 0; k < 9; ++k) {
    *(float4*)&part[k][wv][x0] = float4{dt[0][k], dt[1][k], dt[2][k], dt[3][k]};
    const int r = k / 3, cx = k % 3;   // sq[e][k] = s2[r][e+cx]
    *(float4*)&part[9 + k][wv][x0] = float4{s2[r][cx], s2[r][cx + 1], s2[r][cx + 2], s2[r][cx + 3]};
  }
  *(float4*)&part[18][wv][x0] = float4{sr[0], sr[1], sr[2], sr[3]};
  __syncthreads();

  // thread tid <-> pixel tid for softmax/store
  float td[9], tq[9];
#pragma unroll
  for (int k = 0; k < 9; ++k) {
    td[k] = part[k][0][tid] + part[k][1][tid] + part[k][2][tid] + part[k][3][tid];
    tq[k] = part[9 + k][0][tid] + part[9 + k][1][tid] + part[9 + k][2][tid] + part[9 + k][3][tid];
  }
  const float tsr = part[18][0][tid] + part[18][1][tid] + part[18][2][tid] + part[18][3][tid];

  const float invr = __frsqrt_rn(fmaxf(tsr, 1e-24f));
  float d[9], invp[9];
  float mx = -INFINITY;
#pragma unroll
  for (int k = 0; k < 9; ++k) {
    invp[k] = __frsqrt_rn(fmaxf(tq[k], 1e-24f));
    d[k]    = td[k] * invr * invp[k];
    mx      = fmaxf(mx, d[k]);
  }
  float s = 0.f;
  float cf[9];
#pragma unroll
  for (int k = 0; k < 9; ++k) {
    cf[k] = __expf(d[k] - mx);
    s += cf[k];
  }
  const float sinv = 1.0f / s;

  const int pix = by * W + tid;
#pragma unroll
  for (int k = 0; k < 9; ++k)
    coef[(size_t)k * PIX + pix] = cf[k] * sinv * invp[k];   // patch l2norm folded
}

// ---------------- K2: apply kernel (proven; XCD swizzle, grid=4096) ----------------
__global__ __launch_bounds__(256) void apply_kernel(const float* __restrict__ nbr,
                                                    const float* __restrict__ ref,
                                                    const float* __restrict__ coef,
                                                    float* __restrict__ out) {
  const int blk  = ((blockIdx.x & 7) << 9) | (blockIdx.x >> 3);  // bijective on [0,4096)
  const int gid  = blk * 256 + threadIdx.x;
  const int lane = gid & 63;
  const int x0   = lane * 4;
  const int t    = gid >> 6;
  const int y    = t & 255;
  const int u    = t >> 8;
  const int b    = u >> 5;
  const int c0   = (u & 31) * 2;

  const int ym = (y == 0)     ? 1     : y - 1;
  const int yp = (y == H - 1) ? H - 2 : y + 1;

  const float* n0  = nbr + ((size_t)b * C + c0) * HW;
  const float* n1  = n0 + HW;
  const float* r0p = ref + ((size_t)b * C + c0) * HW;
  float*       o0  = out + ((size_t)b * C + c0) * HW;

  const float4 a0 = *(const float4*)(n0 + ym * W + x0);
  const float4 a1 = *(const float4*)(n0 + y  * W + x0);
  const float4 a2 = *(const float4*)(n0 + yp * W + x0);
  const float4 b0 = *(const float4*)(n1 + ym * W + x0);
  const float4 b1 = *(const float4*)(n1 + y  * W + x0);
  const float4 b2 = *(const float4*)(n1 + yp * W + x0);
  const float4 f0 = *(const float4*)(r0p + y * W + x0);
  const float4 f1 = *(const float4*)(r0p + HW + y * W + x0);

  float La0 = __shfl(a0.w, lane - 1), Ra0 = __shfl(a0.x, lane + 1);
  float La1 = __shfl(a1.w, lane - 1), Ra1 = __shfl(a1.x, lane + 1);
  float La2 = __shfl(a2.w, lane - 1), Ra2 = __shfl(a2.x, lane + 1);
  float Lb0 = __shfl(b0.w, lane - 1), Rb0 = __shfl(b0.x, lane + 1);
  float Lb1 = __shfl(b1.w, lane - 1), Rb1 = __shfl(b1.x, lane + 1);
  float Lb2 = __shfl(b2.w, lane - 1), Rb2 = __shfl(b2.x, lane + 1);
  if (lane == 0)  { La0 = a0.y; La1 = a1.y; La2 = a2.y; Lb0 = b0.y; Lb1 = b1.y; Lb2 = b2.y; }
  if (lane == 63) { Ra0 = a0.z; Ra1 = a1.z; Ra2 = a2.z; Rb0 = b0.z; Rb1 = b1.z; Rb2 = b2.z; }

  float va[3][6] = {{La0, a0.x, a0.y, a0.z, a0.w, Ra0},
                    {La1, a1.x, a1.y, a1.z, a1.w, Ra1},
                    {La2, a2.x, a2.y, a2.z, a2.w, Ra2}};
  float vb[3][6] = {{Lb0, b0.x, b0.y, b0.z, b0.w, Rb0},
                    {Lb1, b1.x, b1.y, b1.z, b1.w, Rb1},
                    {Lb2, b2.x, b2.y, b2.z, b2.w, Rb2}};

  const int cbase = b * HW + y * W + x0;
  float aga[4] = {0.f, 0.f, 0.f, 0.f};
  float agb[4] = {0.f, 0.f, 0.f, 0.f};
#pragma unroll
  for (int k = 0; k < 9; ++k) {
    const float4 cf = *(const float4*)(coef + (size_t)k * PIX + cbase);
    const int r  = k / 3;
    const int cx = k % 3;
    const float cfe[4] = {cf.x, cf.y, cf.z, cf.w};
#pragma unroll
    for (int e = 0; e < 4; ++e) {
      aga[e] = fmaf(cfe[e], va[r][e + cx], aga[e]);
      agb[e] = fmaf(cfe[e], vb[r][e + cx], agb[e]);
    }
  }

  const float ctra[4] = {a1.x, a1.y, a1.z, a1.w};
  const float ctrb[4] = {b1.x, b1.y, b1.z, b1.w};
  const float rfa[4]  = {f0.x, f0.y, f0.z, f0.w};
  const float rfb[4]  = {f1.x, f1.y, f1.z, f1.w};
  float oae[4], obe[4];
#pragma unroll
  for (int e = 0; e < 4; ++e) {
    const float da = ctra[e] - rfa[e];
    const float db = ctrb[e] - rfb[e];
    oae[e] = aga[e] * __expf(-(da * da));
    obe[e] = agb[e] * __expf(-(db * db));
  }
  float4 oa, ob4;
  oa.x = oae[0]; oa.y = oae[1]; oa.z = oae[2]; oa.w = oae[3];
  ob4.x = obe[0]; ob4.y = obe[1]; ob4.z = obe[2]; ob4.w = obe[3];

  *(float4*)(o0 + y * W + x0) = oa;
  *(float4*)(o0 + HW + y * W + x0) = ob4;
}

// ---------------- fallback: R4 fused kernel (if ws too small) ----------------
__global__ __launch_bounds__(256) void fused_nbr_attn(const float* __restrict__ nbr,
                                                      const float* __restrict__ ref,
                                                      float* __restrict__ out) {
  const int tid  = threadIdx.x;
  const int lane = tid & 63;
  const int wv   = tid >> 6;
  const int px   = lane & 7;
  const int cg   = lane >> 3;

  const int pix = blockIdx.x * 32 + wv * 8 + px;
  const int b   = pix >> 16;
  const int p   = pix & (HW - 1);
  const int y   = p >> 8;
  const int x   = p & (W - 1);

  const int ym = (y == 0)     ? 1     : y - 1;
  const int yp = (y == H - 1) ? H - 2 : y + 1;
  const int xm = (x == 0)     ? 1     : x - 1;
  const int xp = (x == W - 1) ? W - 2 : x + 1;

  int off[9];
  off[0] = ym * W + xm; off[1] = ym * W + x; off[2] = ym * W + xp;
  off[3] = y  * W + xm; off[4] = y  * W + x; off[5] = y  * W + xp;
  off[6] = yp * W + xm; off[7] = yp * W + x; off[8] = yp * W + xp;
  const int ctr = y * W + x;

  const float* nb = nbr + ((size_t)b * C + cg * 8) * HW;
  const float* rb = ref + ((size_t)b * C + cg * 8) * HW;
  float*       ob = out + ((size_t)b * C + cg * 8) * HW;

  float v[8][9], r[8];
#pragma unroll
  for (int j = 0; j < 8; ++j) {
    r[j] = rb[j * HW + ctr];
#pragma unroll
    for (int k = 0; k < 9; ++k) v[j][k] = nb[j * HW + off[k]];
  }
  float sr = 0.f;
  float dot[9], ss[9];
#pragma unroll
  for (int k = 0; k < 9; ++k) { dot[k] = 0.f; ss[k] = 0.f; }
#pragma unroll
  for (int j = 0; j < 8; ++j) {
    sr = fmaf(r[j], r[j], sr);
#pragma unroll
    for (int k = 0; k < 9; ++k) {
      dot[k] = fmaf(r[j], v[j][k], dot[k]);
      ss[k]  = fmaf(v[j][k], v[j][k], ss[k]);
    }
  }
#pragma unroll
  for (int m = 8; m < 64; m <<= 1) {
    sr += __shfl_xor(sr, m);
#pragma unroll
    for (int k = 0; k < 9; ++k) {
      dot[k] += __shfl_xor(dot[k], m);
      ss[k]  += __shfl_xor(ss[k], m);
    }
  }
  const float invr = __frsqrt_rn(fmaxf(sr, 1e-24f));
  float d[9], invp[9];
  float mx = -INFINITY;
#pragma unroll
  for (int k = 0; k < 9; ++k) {
    invp[k] = __frsqrt_rn(fmaxf(ss[k], 1e-24f));
    d[k]    = dot[k] * invr * invp[k];
    mx      = fmaxf(mx, d[k]);
  }
  float s = 0.f;
  float coef[9];
#pragma unroll
  for (int k = 0; k < 9; ++k) {
    const float e = __expf(d[k] - mx);
    coef[k] = e;
    s += e;
  }
  const float sinv = 1.0f / s;
#pragma unroll
  for (int k = 0; k < 9; ++k) coef[k] *= sinv * invp[k];
#pragma unroll
  for (int j = 0; j < 8; ++j) {
    float a = 0.f;
#pragma unroll
    for (int k = 0; k < 9; ++k) a = fmaf(coef[k], v[j][k], a);
    const float diff = v[j][4] - r[j];
    const float wd   = __expf(-(diff * diff));
    ob[j * HW + ctr] = a * wd;
  }
}

extern "C" void kernel_launch(void* const* d_in, const int* in_sizes, int n_in,
                              void* d_out, int out_size, void* d_ws, size_t ws_size,
                              hipStream_t stream) {
  const float* nbr = (const float*)d_in[0];
  const float* ref = (const float*)d_in[1];
  float*       out = (float*)d_out;
  const size_t coef_bytes = (size_t)9 * PIX * sizeof(float);

  if (ws_size >= coef_bytes) {
    float* coef = (float*)d_ws;
    coef7_kernel<<<dim3(B * H), dim3(256), 0, stream>>>(nbr, ref, coef);     // 512 row-blocks
    apply_kernel<<<dim3(PIX / 4 * (C / 2) / 256), dim3(256), 0, stream>>>(nbr, ref, coef, out);  // 4096
  } else {
    fused_nbr_attn<<<dim3(PIX / 32), dim3(256), 0, stream>>>(nbr, ref, out);
  }
}